// Round 9
// baseline (979.572 us; speedup 1.0000x reference)
//
#include <hip/hip_runtime.h>
#include <hip/hip_bf16.h>

#define DIM      512
#define NSTEPS   16
#define BATCH    4096

// d_out offsets (f32 elements)
#define OFF_XF   0
#define OFF_VF   2097152
#define OFF_POS  4194304
#define OFF_VEL  39845888
#define OFF_GZ   75497472
#define OFF_CONV 75497489
#define SLAB     2097152

// d_ws layout (bytes)
#define WS_WV 0
#define WS_W1 524288
#define WS_W2 1048576
#define WS_GZ 1572864

#define TOT_TILES 528   // 16 (Wv) + 16 steps * 32 (W1a + W2)

typedef __attribute__((ext_vector_type(8))) short short8v;  // 8 bf16
typedef __attribute__((ext_vector_type(4))) float f32x4;

__device__ __forceinline__ unsigned short f2bf(float f) {
  union { float f; unsigned u; } a; a.f = f;
  return (unsigned short)((a.u + 0x7FFFu + ((a.u >> 16) & 1u)) >> 16);
}

__device__ __forceinline__ float tanh_fast(float x) {
  float e = __expf(2.0f * x);
  return 1.0f - 2.0f / (e + 1.0f);
}

// swizzled bf16 store into [32][512] LDS tile (row stride 1024 B, XOR bits 4-6)
__device__ __forceinline__ void st_bf(unsigned short* lds, int r, int c, float f) {
  int byte = (c << 1) ^ ((r & 7) << 4);
  *(unsigned short*)((char*)lds + (r << 10) + byte) = f2bf(f);
}

// ---- prep: f32 weights -> bf16 K-tile-major fragment layout; zero gz sums ----
// per matrix: tile T (0..15, k=T*32), nt (0..31), lane, j:
//   value W[nt*16 + (lane&15)][T*32 + (lane>>4)*8 + j]
//   at ushort offset ((T*32 + nt)*64 + lane)*8 + j   (tile = 32 KB contiguous)
__global__ void prep_kernel(const float* __restrict__ Wv,
                            const float* __restrict__ W1,
                            const float* __restrict__ W2,
                            unsigned short* __restrict__ ws) {
  int t = blockIdx.x * 256 + threadIdx.x;          // 3*32768 = 98304 threads
  if (t < 64) ((float*)(ws + WS_GZ / 2))[t] = 0.0f;
  int mat = t >> 15, idx = t & 32767;
  int lane = idx & 63, nt = (idx >> 6) & 31, T = idx >> 11;
  const float* W = (mat == 0) ? Wv : (mat == 1) ? W1 : W2;
  int stride = (mat == 1) ? 1024 : 512;            // W1 is (512,1024); cols [0,512)
  unsigned short* o = ws + (mat == 0 ? WS_WV / 2 : (mat == 1) ? WS_W1 / 2 : WS_W2 / 2);
  int row = nt * 16 + (lane & 15);
  int col = T * 32 + (lane >> 4) * 8;
  const float* src = W + row * stride + col;
  short8v v;
#pragma unroll
  for (int j = 0; j < 8; ++j) v[j] = (short)f2bf(src[j]);
  *(short8v*)(o + ((T * 32 + nt) * 64 + lane) * 8) = v;
}

// ---- wave-private B-slice issue: wave w stages its own 2 KB of the tile ----
// slice = n-tiles 2w, 2w+1 -> tile bytes [w*2048, w*2048+2048)
__device__ __forceinline__ void issue_tile(int abs2, const char* wsv, const char* ws1,
                                           const char* ws2, unsigned short* lds_b,
                                           int w2048, int lane16) {
  if (abs2 >= TOT_TILES) return;
  const char* mb; int T;
  if (abs2 < 16) { mb = wsv; T = abs2; }
  else { int rel = abs2 - 16; T = rel & 15; mb = ((rel >> 4) & 1) ? ws2 : ws1; }
  const char* src = mb + (T << 15) + w2048 + lane16;
  char* dst = (char*)lds_b + (abs2 % 3) * 32768 + w2048;
  __builtin_amdgcn_global_load_lds(
      (const __attribute__((address_space(1))) void*)src,
      (__attribute__((address_space(3))) void*)dst, 16, 0, 0);
  __builtin_amdgcn_global_load_lds(
      (const __attribute__((address_space(1))) void*)(src + 1024),
      (__attribute__((address_space(3))) void*)(dst + 1024), 16, 0, 0);
}

// ---- per-tile compute: 2 A ds_read + 2 B ds_read_b128 + 4 MFMA ----
__device__ __forceinline__ void tile_compute(int bufi, int T, const unsigned short* lds_b,
                                             const char* aptr0, const char* aptr1,
                                             int acol0, int aswz, int boff, f32x4 acc[2][2]) {
  int aoff = (T * 64 + acol0) ^ aswz;
  short8v a0 = *(const short8v*)(aptr0 + aoff);
  short8v a1 = *(const short8v*)(aptr1 + aoff);
  const unsigned short* bb = lds_b + bufi * 16384 + boff;
  short8v b0 = *(const short8v*)(bb);
  short8v b1 = *(const short8v*)(bb + 512);
  acc[0][0] = __builtin_amdgcn_mfma_f32_16x16x32_bf16(a0, b0, acc[0][0], 0, 0, 0);
  acc[0][1] = __builtin_amdgcn_mfma_f32_16x16x32_bf16(a0, b1, acc[0][1], 0, 0, 0);
  acc[1][0] = __builtin_amdgcn_mfma_f32_16x16x32_bf16(a1, b0, acc[1][0], 0, 0, 0);
  acc[1][1] = __builtin_amdgcn_mfma_f32_16x16x32_bf16(a1, b1, acc[1][1], 0, 0, 0);
}

#define WAITV(n) asm volatile("s_waitcnt vmcnt(" #n ")" ::: "memory")
#define LGKM0    asm volatile("s_waitcnt lgkmcnt(0)" ::: "memory")
#define BAR      __builtin_amdgcn_s_barrier()

#define ZACC do { acc[0][0] = (f32x4){0.f,0.f,0.f,0.f}; acc[0][1] = (f32x4){0.f,0.f,0.f,0.f}; \
                  acc[1][0] = (f32x4){0.f,0.f,0.f,0.f}; acc[1][1] = (f32x4){0.f,0.f,0.f,0.f}; } while (0)

// ---- main persistent kernel: 128 blocks x 1024 thr, 32 rows/block ----
__global__ __launch_bounds__(1024)
void main_kernel(const float* __restrict__ x0,
                 const float* __restrict__ noise,
                 const float* __restrict__ bv,
                 const float* __restrict__ b1,
                 const float* __restrict__ b2,
                 const float* __restrict__ Wg1,
                 const float* __restrict__ bg1,
                 const float* __restrict__ Wg2,
                 const float* __restrict__ bg2,
                 const float* __restrict__ rdecay,
                 const float* __restrict__ rdt,
                 const float* __restrict__ rspring,
                 const float* __restrict__ rthr,
                 const unsigned short* __restrict__ ws,
                 float* __restrict__ gzsum,
                 float* __restrict__ out) {
  __shared__ unsigned short lds_b[49152];   // 3 x 32 KB B-tile buffers
  __shared__ unsigned short a_lds[16384];   // [32][512] bf16 x/h tile, swizzled
  __shared__ float gz_p[32];
  __shared__ float gate_lds[32];

  const int tid  = threadIdx.x;
  const int lane = tid & 63;
  const int w    = tid >> 6;       // 16 waves; wave w owns cols [w*32, w*32+32)
  const int lg   = lane >> 4;
  const int li   = lane & 15;
  const int base = blockIdx.x * 32;

  const char* wsv = (const char*)ws + WS_WV;
  const char* ws1 = (const char*)ws + WS_W1;
  const char* ws2 = (const char*)ws + WS_W2;
  const int w2048  = w * 2048;           // byte offset of wave slice in tile
  const int lane16 = lane * 16;
  const char* aptr0 = (const char*)a_lds + li * 1024;          // m-tile 0: rows 0-15
  const char* aptr1 = (const char*)a_lds + (16 + li) * 1024;   // m-tile 1: rows 16-31
  const int acol0 = lg * 16;
  const int aswz  = (li & 7) << 4;
  const int boff  = w * 1024 + lane * 8; // ushort offset of this lane's B frags

  // start the B pipeline immediately
  issue_tile(0, wsv, ws1, ws2, lds_b, w2048, lane16);
  issue_tile(1, wsv, ws1, ws2, lds_b, w2048, lane16);

  const float decay  = fminf(fmaxf(rdecay[0], 0.5f), 0.99f);
  const float dt     = fminf(fmaxf(rdt[0], 0.01f), 0.5f);
  const float spring = fabsf(rspring[0]) + 0.01f;

  int colv[2];
  float b1c[2], b2c[2], bvc[2];
#pragma unroll
  for (int q = 0; q < 2; ++q) {
    colv[q] = w * 32 + q * 16 + li;
    b1c[q] = b1[colv[q]]; b2c[q] = b2[colv[q]]; bvc[q] = bv[colv[q]];
  }
  int rowv[2][4], rg[2][4];
#pragma unroll
  for (int m = 0; m < 2; ++m)
#pragma unroll
    for (int j = 0; j < 4; ++j) {
      rowv[m][j] = m * 16 + lg * 4 + j;
      rg[m][j] = (base + rowv[m][j]) * DIM;
    }

  // ---- prologue: stage x0 -> LDS (bf16), positions[0], load x state ----
  if (tid < 32) gz_p[tid] = 0.0f;
  for (int i = tid; i < 4096; i += 1024) {
    int r = i >> 7, c4 = (i & 127) * 4;
    f32x4 xv = *(const f32x4*)&x0[(base + r) * DIM + c4];
    st_bf(a_lds, r, c4 + 0, xv.x); st_bf(a_lds, r, c4 + 1, xv.y);
    st_bf(a_lds, r, c4 + 2, xv.z); st_bf(a_lds, r, c4 + 3, xv.w);
    *(f32x4*)&out[OFF_POS + (size_t)(base + r) * DIM + c4] = xv;
  }
  float x[2][2][4], v[2][2][4];
#pragma unroll
  for (int m = 0; m < 2; ++m)
#pragma unroll
    for (int q = 0; q < 2; ++q)
#pragma unroll
      for (int j = 0; j < 4; ++j) x[m][q][j] = x0[rg[m][j] + colv[q]];
  LGKM0; BAR;

  f32x4 acc[2][2];
  ZACC;
  // ---- v0 = x0 @ Wv^T + bv : tiles 0..15 (barrier-free, self-paced) ----
#pragma unroll
  for (int T = 0; T < 16; ++T) {
    issue_tile(T + 2, wsv, ws1, ws2, lds_b, w2048, lane16);
    WAITV(4);
    tile_compute(T % 3, T, lds_b, aptr0, aptr1, acol0, aswz, boff, acc);
  }
#pragma unroll
  for (int m = 0; m < 2; ++m)
#pragma unroll
    for (int q = 0; q < 2; ++q)
#pragma unroll
      for (int j = 0; j < 4; ++j) {
        v[m][q][j] = acc[m][q][j] + bvc[q];
        out[OFF_VEL + rg[m][j] + colv[q]] = v[m][q][j];   // velocities[0]
      }

  // ---- 16 steps ----
  for (int t = 0; t < NSTEPS; ++t) {
    const int sb = 16 + t * 32;

    // phase A: stage x(t) (t>0), noise prefetch, ||v||^2 reduce
    BAR;                                    // a_lds free (all waves past reads)
    if (t > 0) {
#pragma unroll
      for (int m = 0; m < 2; ++m)
#pragma unroll
        for (int q = 0; q < 2; ++q)
#pragma unroll
          for (int j = 0; j < 4; ++j) st_bf(a_lds, rowv[m][j], colv[q], x[m][q][j]);
    }
    float nz[2][2][4];
    {
      const float* np = noise + (size_t)t * (BATCH * DIM);
#pragma unroll
      for (int m = 0; m < 2; ++m)
#pragma unroll
        for (int q = 0; q < 2; ++q)
#pragma unroll
          for (int j = 0; j < 4; ++j) nz[m][q][j] = np[rg[m][j] + colv[q]];
    }
#pragma unroll
    for (int m = 0; m < 2; ++m)
#pragma unroll
      for (int j = 0; j < 4; ++j) {
        float s = 0.f;
#pragma unroll
        for (int q = 0; q < 2; ++q) s += v[m][q][j] * v[m][q][j];
        s += __shfl_xor(s, 1); s += __shfl_xor(s, 2);
        s += __shfl_xor(s, 4); s += __shfl_xor(s, 8);
        if (li == 0) atomicAdd(&gz_p[rowv[m][j]], s);
      }
    LGKM0; BAR;                             // b1: x staged + gz_p complete

    // gate MLP (one lane per row) + gray-zone partial
    if (tid < 32) {
      float g = sqrtf(gz_p[tid]);
      gz_p[tid] = 0.0f;                     // re-zero for next step
      float z = bg2[0];
#pragma unroll
      for (int k = 0; k < 32; ++k) {
        float a = fmaxf(fmaf(g, Wg1[k], bg1[k]), 0.0f);
        z = fmaf(Wg2[k], a, z);
      }
      gate_lds[tid] = 1.0f / (1.0f + __expf(-z));
      float bs = g;
      bs += __shfl_xor(bs, 1); bs += __shfl_xor(bs, 2);
      bs += __shfl_xor(bs, 4); bs += __shfl_xor(bs, 8);
      bs += __shfl_xor(bs, 16);
      if (tid == 0) {
        atomicAdd(&gzsum[t + 1], bs);
        if (t == 0) atomicAdd(&gzsum[0], bs);   // gray_zones[0] == gray_zones[1]
      }
    }
    LGKM0; BAR;                             // b2: gate_lds + gz_p-zero visible

    // GEMM1: z1 = x @ W1a^T  (tiles sb..sb+15, barrier-free)
    ZACC;
#pragma unroll
    for (int T = 0; T < 16; ++T) {
      issue_tile(sb + T + 2, wsv, ws1, ws2, lds_b, w2048, lane16);
      WAITV(4);
      tile_compute((sb + T) % 3, T, lds_b, aptr0, aptr1, acol0, aswz, boff, acc);
    }
    BAR;                                    // b3: all waves done G1 A-reads
    // stage h = tanh(z1 + b1)
#pragma unroll
    for (int m = 0; m < 2; ++m)
#pragma unroll
      for (int q = 0; q < 2; ++q)
#pragma unroll
        for (int j = 0; j < 4; ++j)
          st_bf(a_lds, rowv[m][j], colv[q], tanh_fast(acc[m][q][j] + b1c[q]));
    LGKM0; BAR;                             // b4: h staged

    // GEMM2: f = h @ W2^T  (tiles sb+16..sb+31, barrier-free)
    ZACC;
#pragma unroll
    for (int T = 0; T < 16; ++T) {
      issue_tile(sb + 18 + T, wsv, ws1, ws2, lds_b, w2048, lane16);
      if (t == NSTEPS - 1 && T >= 14) {
        if (T == 14) { WAITV(2); } else { WAITV(0); }
      } else {
        WAITV(4);
      }
      tile_compute((sb + 16 + T) % 3, T, lds_b, aptr0, aptr1, acol0, aswz, boff, acc);
    }

    // epilogue: update + stream outputs
    float* pos = out + OFF_POS + (size_t)(t + 1) * SLAB;
    float* vel = out + OFF_VEL + (size_t)(t + 1) * SLAB;
#pragma unroll
    for (int m = 0; m < 2; ++m)
#pragma unroll
      for (int j = 0; j < 4; ++j) {
        float g = gate_lds[rowv[m][j]];
#pragma unroll
        for (int q = 0; q < 2; ++q) {
          float force = spring * (acc[m][q][j] + b2c[q]);
          float vn = fmaf(decay, v[m][q][j], force) + nz[m][q][j] * g * 0.1f;
          v[m][q][j] = vn;
          x[m][q][j] = fmaf(dt, vn, x[m][q][j]);
          int gi = rg[m][j] + colv[q];
          pos[gi] = x[m][q][j];
          vel[gi] = vn;
          if (t == NSTEPS - 1) { out[OFF_XF + gi] = x[m][q][j]; out[OFF_VF + gi] = vn; }
        }
      }
  }

  // ---- converged = ||v_f|| < threshold (gz_p zeroed in last gate phase) ----
#pragma unroll
  for (int m = 0; m < 2; ++m)
#pragma unroll
    for (int j = 0; j < 4; ++j) {
      float s = 0.f;
#pragma unroll
      for (int q = 0; q < 2; ++q) s += v[m][q][j] * v[m][q][j];
      s += __shfl_xor(s, 1); s += __shfl_xor(s, 2);
      s += __shfl_xor(s, 4); s += __shfl_xor(s, 8);
      if (li == 0) atomicAdd(&gz_p[rowv[m][j]], s);
    }
  LGKM0; BAR;
  if (tid < 32) {
    float thr = fabsf(rthr[0]) + 1e-4f;
    out[OFF_CONV + base + tid] = (sqrtf(gz_p[tid]) < thr) ? 1.0f : 0.0f;
  }
}

__global__ void finalize_kernel(const float* __restrict__ gzsum,
                                float* __restrict__ out) {
  int t = threadIdx.x;
  if (t < 17) out[OFF_GZ + t] = gzsum[t] * (1.0f / 4096.0f);
}

extern "C" void kernel_launch(void* const* d_in, const int* in_sizes, int n_in,
                              void* d_out, int out_size, void* d_ws, size_t ws_size,
                              hipStream_t stream) {
  const float* x0     = (const float*)d_in[0];
  const float* noise  = (const float*)d_in[1];
  const float* Wv     = (const float*)d_in[2];
  const float* bv     = (const float*)d_in[3];
  const float* W1     = (const float*)d_in[4];
  const float* b1     = (const float*)d_in[5];
  const float* W2     = (const float*)d_in[6];
  const float* b2     = (const float*)d_in[7];
  const float* Wg1    = (const float*)d_in[8];
  const float* bg1    = (const float*)d_in[9];
  const float* Wg2    = (const float*)d_in[10];
  const float* bg2    = (const float*)d_in[11];
  const float* rdec   = (const float*)d_in[12];
  const float* rdt    = (const float*)d_in[13];
  const float* rspr   = (const float*)d_in[14];
  const float* rthr   = (const float*)d_in[15];
  unsigned short* ws  = (unsigned short*)d_ws;
  float* gz           = (float*)((char*)d_ws + WS_GZ);
  float* out          = (float*)d_out;

  prep_kernel<<<384, 256, 0, stream>>>(Wv, W1, W2, ws);
  main_kernel<<<128, 1024, 0, stream>>>(x0, noise, bv, b1, b2, Wg1, bg1, Wg2, bg2,
                                        rdec, rdt, rspr, rthr, ws, gz, out);
  finalize_kernel<<<1, 32, 0, stream>>>(gz, out);
}

// Round 10
// 611.421 us; speedup vs baseline: 1.6021x; 1.6021x over previous
//
#include <hip/hip_runtime.h>
#include <hip/hip_bf16.h>

#define DIM      512
#define NSTEPS   16
#define BATCH    4096

// d_out offsets (f32 elements)
#define OFF_XF   0
#define OFF_VF   2097152
#define OFF_POS  4194304
#define OFF_VEL  39845888
#define OFF_GZ   75497472
#define OFF_CONV 75497489
#define SLAB     2097152

// d_ws layout (bytes)
#define WS_WV 0
#define WS_W1 524288
#define WS_W2 1048576
#define WS_GZ 1572864

#define TOT_TILES 528   // 16 (Wv) + 16 steps * 32 (W1a + W2)

typedef __attribute__((ext_vector_type(8))) short short8v;  // 8 bf16
typedef __attribute__((ext_vector_type(4))) float f32x4;

__device__ __forceinline__ unsigned short f2bf(float f) {
  union { float f; unsigned u; } a; a.f = f;
  return (unsigned short)((a.u + 0x7FFFu + ((a.u >> 16) & 1u)) >> 16);
}

__device__ __forceinline__ float tanh_fast(float x) {
  float e = __expf(2.0f * x);
  return 1.0f - 2.0f / (e + 1.0f);
}

// swizzled bf16 store into [16][512] LDS tile (row stride 1024 B, XOR bits 4-6)
__device__ __forceinline__ void st_bf(unsigned short* lds, int r, int c, float f) {
  int byte = (c << 1) ^ ((r & 7) << 4);
  *(unsigned short*)((char*)lds + (r << 10) + byte) = f2bf(f);
}

// ---- prep: f32 weights -> bf16 K-tile-major fragment layout; zero gz sums ----
__global__ void prep_kernel(const float* __restrict__ Wv,
                            const float* __restrict__ W1,
                            const float* __restrict__ W2,
                            unsigned short* __restrict__ ws) {
  int t = blockIdx.x * 256 + threadIdx.x;          // 3*32768 = 98304 threads
  if (t < 64) ((float*)(ws + WS_GZ / 2))[t] = 0.0f;
  int mat = t >> 15, idx = t & 32767;
  int lane = idx & 63, nt = (idx >> 6) & 31, T = idx >> 11;
  const float* W = (mat == 0) ? Wv : (mat == 1) ? W1 : W2;
  int stride = (mat == 1) ? 1024 : 512;            // W1 is (512,1024); cols [0,512)
  unsigned short* o = ws + (mat == 0 ? WS_WV / 2 : (mat == 1) ? WS_W1 / 2 : WS_W2 / 2);
  int row = nt * 16 + (lane & 15);
  int col = T * 32 + (lane >> 4) * 8;
  const float* src = W + row * stride + col;
  short8v v;
#pragma unroll
  for (int j = 0; j < 8; ++j) v[j] = (short)f2bf(src[j]);
  *(short8v*)(o + ((T * 32 + nt) * 64 + lane) * 8) = v;
}

// ---- wave-private B-slice issue: wave w stages its own 2 KB of the tile ----
__device__ __forceinline__ void issue_tile(int abs2, const char* wsv, const char* ws1,
                                           const char* ws2, unsigned short* lds_b,
                                           int w2048, int lane16) {
  if (abs2 >= TOT_TILES) return;
  const char* mb; int T;
  if (abs2 < 16) { mb = wsv; T = abs2; }
  else { int rel = abs2 - 16; T = rel & 15; mb = ((rel >> 4) & 1) ? ws2 : ws1; }
  const char* src = mb + (T << 15) + w2048 + lane16;
  char* dst = (char*)lds_b + (abs2 % 3) * 32768 + w2048;
  __builtin_amdgcn_global_load_lds(
      (const __attribute__((address_space(1))) void*)src,
      (__attribute__((address_space(3))) void*)dst, 16, 0, 0);
  __builtin_amdgcn_global_load_lds(
      (const __attribute__((address_space(1))) void*)(src + 1024),
      (__attribute__((address_space(3))) void*)(dst + 1024), 16, 0, 0);
}

// ---- per-tile compute: 1 A ds_read + 2 B ds_read_b128 + 2 MFMA (wave-private) ----
__device__ __forceinline__ void tile_compute(int bufi, int T, const unsigned short* lds_b,
                                             const char* aptr, int acol0, int aswz,
                                             int boff, f32x4* acc) {
  short8v a = *(const short8v*)(aptr + ((T * 64 + acol0) ^ aswz));
  const unsigned short* bb = lds_b + bufi * 16384 + boff;
  short8v b0 = *(const short8v*)(bb);
  short8v b1 = *(const short8v*)(bb + 512);
  acc[0] = __builtin_amdgcn_mfma_f32_16x16x32_bf16(a, b0, acc[0], 0, 0, 0);
  acc[1] = __builtin_amdgcn_mfma_f32_16x16x32_bf16(a, b1, acc[1], 0, 0, 0);
}

#define WAITV(n) asm volatile("s_waitcnt vmcnt(" #n ")" ::: "memory")
#define LGKM0    asm volatile("s_waitcnt lgkmcnt(0)" ::: "memory")
#define BAR      __builtin_amdgcn_s_barrier()

// ---- main persistent kernel: 256 blocks x 1024 thr, 16 rows/block ----
__global__ __attribute__((amdgpu_flat_work_group_size(1024, 1024)))
__attribute__((amdgpu_waves_per_eu(4, 4)))
void main_kernel(const float* __restrict__ x0,
                 const float* __restrict__ noise,
                 const float* __restrict__ bv,
                 const float* __restrict__ b1,
                 const float* __restrict__ b2,
                 const float* __restrict__ Wg1,
                 const float* __restrict__ bg1,
                 const float* __restrict__ Wg2,
                 const float* __restrict__ bg2,
                 const float* __restrict__ rdecay,
                 const float* __restrict__ rdt,
                 const float* __restrict__ rspring,
                 const float* __restrict__ rthr,
                 const unsigned short* __restrict__ ws,
                 float* __restrict__ gzsum,
                 float* __restrict__ out) {
  __shared__ unsigned short lds_b[49152];   // 3 x 32 KB B-tile buffers
  __shared__ unsigned short a_lds[8192];    // [16][512] bf16 x/h tile, swizzled
  __shared__ float x_lds[8192];             // [16][512] f32 x state
  __shared__ float gz_p[16];
  __shared__ float gate_lds[16];

  const int tid  = threadIdx.x;
  const int lane = tid & 63;
  const int w    = tid >> 6;       // 16 waves; wave w owns cols [w*32, w*32+32)
  const int lg   = lane >> 4;
  const int li   = lane & 15;
  const int base = blockIdx.x * 16;

  const char* wsv = (const char*)ws + WS_WV;
  const char* ws1 = (const char*)ws + WS_W1;
  const char* ws2 = (const char*)ws + WS_W2;
  const int w2048  = w * 2048;           // byte offset of wave slice in tile
  const int lane16 = lane * 16;
  const char* aptr = (const char*)a_lds + li * 1024;
  const int acol0 = lg * 16;
  const int aswz  = (li & 7) << 4;
  const int boff  = w * 1024 + lane * 8; // ushort offset of this lane's B frags

  // start the B pipeline immediately
  issue_tile(0, wsv, ws1, ws2, lds_b, w2048, lane16);
  issue_tile(1, wsv, ws1, ws2, lds_b, w2048, lane16);

  const float decay  = fminf(fmaxf(rdecay[0], 0.5f), 0.99f);
  const float dt     = fminf(fmaxf(rdt[0], 0.01f), 0.5f);
  const float spring = fabsf(rspring[0]) + 0.01f;

  int colv[2];
  float b1c[2], b2c[2], bvc[2];
#pragma unroll
  for (int q = 0; q < 2; ++q) {
    colv[q] = w * 32 + q * 16 + li;
    b1c[q] = b1[colv[q]]; b2c[q] = b2[colv[q]]; bvc[q] = bv[colv[q]];
  }
  int rowv[4], rg[4];
#pragma unroll
  for (int j = 0; j < 4; ++j) { rowv[j] = lg * 4 + j; rg[j] = (base + rowv[j]) * DIM; }

  // ---- prologue: stage x0 -> a_lds (bf16) + x_lds (f32), positions[0] ----
  if (tid < 16) gz_p[tid] = 0.0f;
  for (int i = tid; i < 2048; i += 1024) {
    int r = i >> 7, c4 = (i & 127) * 4;
    f32x4 xv = *(const f32x4*)&x0[(base + r) * DIM + c4];
    st_bf(a_lds, r, c4 + 0, xv.x); st_bf(a_lds, r, c4 + 1, xv.y);
    st_bf(a_lds, r, c4 + 2, xv.z); st_bf(a_lds, r, c4 + 3, xv.w);
    *(f32x4*)&x_lds[r * 512 + c4] = xv;
    *(f32x4*)&out[OFF_POS + (size_t)(base + r) * DIM + c4] = xv;
  }
  float v[2][4];
  LGKM0; BAR;

  f32x4 acc[2];
  acc[0] = (f32x4){0.f, 0.f, 0.f, 0.f};
  acc[1] = (f32x4){0.f, 0.f, 0.f, 0.f};
  // ---- v0 = x0 @ Wv^T + bv : tiles 0..15 (barrier-free, self-paced) ----
#pragma unroll
  for (int T = 0; T < 16; ++T) {
    issue_tile(T + 2, wsv, ws1, ws2, lds_b, w2048, lane16);
    WAITV(4);
    tile_compute(T % 3, T, lds_b, aptr, acol0, aswz, boff, acc);
  }
#pragma unroll
  for (int q = 0; q < 2; ++q)
#pragma unroll
    for (int j = 0; j < 4; ++j) {
      v[q][j] = acc[q][j] + bvc[q];
      out[OFF_VEL + rg[j] + colv[q]] = v[q][j];   // velocities[0]
    }

  // ---- 16 steps ----
  for (int t = 0; t < NSTEPS; ++t) {
    const int sb = 16 + t * 32;

    // phase A: stage x(t) from x_lds (t>0), ||v||^2 reduce
    LGKM0; BAR;                             // a_lds free (all waves past reads)
    if (t > 0) {
#pragma unroll
      for (int q = 0; q < 2; ++q)
#pragma unroll
        for (int j = 0; j < 4; ++j)
          st_bf(a_lds, rowv[j], colv[q], x_lds[rowv[j] * 512 + colv[q]]);
    }
#pragma unroll
    for (int j = 0; j < 4; ++j) {
      float s = 0.f;
#pragma unroll
      for (int q = 0; q < 2; ++q) s += v[q][j] * v[q][j];
      s += __shfl_xor(s, 1); s += __shfl_xor(s, 2);
      s += __shfl_xor(s, 4); s += __shfl_xor(s, 8);
      if (li == 0) atomicAdd(&gz_p[rowv[j]], s);
    }
    LGKM0; BAR;                             // b1: x staged + gz_p complete

    // gate MLP (one lane per row) + gray-zone partial
    if (tid < 16) {
      float g = sqrtf(gz_p[tid]);
      gz_p[tid] = 0.0f;                     // re-zero for next step
      float z = bg2[0];
#pragma unroll
      for (int k = 0; k < 32; ++k) {
        float a = fmaxf(fmaf(g, Wg1[k], bg1[k]), 0.0f);
        z = fmaf(Wg2[k], a, z);
      }
      gate_lds[tid] = 1.0f / (1.0f + __expf(-z));
      float bs = g;
      bs += __shfl_xor(bs, 1); bs += __shfl_xor(bs, 2);
      bs += __shfl_xor(bs, 4); bs += __shfl_xor(bs, 8);
      if (tid == 0) {
        atomicAdd(&gzsum[t + 1], bs);
        if (t == 0) atomicAdd(&gzsum[0], bs);   // gray_zones[0] == gray_zones[1]
      }
    }
    LGKM0; BAR;                             // b2: gate_lds + gz_p-zero visible

    // GEMM1: z1 = x @ W1a^T  (tiles sb..sb+15, barrier-free)
    acc[0] = (f32x4){0.f, 0.f, 0.f, 0.f};
    acc[1] = (f32x4){0.f, 0.f, 0.f, 0.f};
#pragma unroll
    for (int T = 0; T < 16; ++T) {
      issue_tile(sb + T + 2, wsv, ws1, ws2, lds_b, w2048, lane16);
      WAITV(4);
      tile_compute((sb + T) % 3, T, lds_b, aptr, acol0, aswz, boff, acc);
    }
    BAR;                                    // b3: all waves done G1 A-reads
    // stage h = tanh(z1 + b1)
#pragma unroll
    for (int q = 0; q < 2; ++q)
#pragma unroll
      for (int j = 0; j < 4; ++j)
        st_bf(a_lds, rowv[j], colv[q], tanh_fast(acc[q][j] + b1c[q]));
    LGKM0; BAR;                             // b4: h staged

    // noise loads (older than all GEMM2 tile ops -> retired by counted waits)
    float nz[2][4];
    {
      const float* np = noise + (size_t)t * (BATCH * DIM);
#pragma unroll
      for (int q = 0; q < 2; ++q)
#pragma unroll
        for (int j = 0; j < 4; ++j) nz[q][j] = np[rg[j] + colv[q]];
    }

    // GEMM2: f = h @ W2^T  (tiles sb+16..sb+31, barrier-free)
    acc[0] = (f32x4){0.f, 0.f, 0.f, 0.f};
    acc[1] = (f32x4){0.f, 0.f, 0.f, 0.f};
#pragma unroll
    for (int T = 0; T < 16; ++T) {
      issue_tile(sb + 18 + T, wsv, ws1, ws2, lds_b, w2048, lane16);
      if (t == NSTEPS - 1 && T >= 14) {
        if (T == 14) { WAITV(2); } else { WAITV(0); }
      } else {
        WAITV(4);
      }
      tile_compute((sb + 16 + T) % 3, T, lds_b, aptr, acol0, aswz, boff, acc);
    }

    // epilogue: update v (regs) + x (x_lds) + stream outputs
    float* pos = out + OFF_POS + (size_t)(t + 1) * SLAB;
    float* vel = out + OFF_VEL + (size_t)(t + 1) * SLAB;
#pragma unroll
    for (int j = 0; j < 4; ++j) {
      float g = gate_lds[rowv[j]];
#pragma unroll
      for (int q = 0; q < 2; ++q) {
        float force = spring * (acc[q][j] + b2c[q]);
        float vn = fmaf(decay, v[q][j], force) + nz[q][j] * g * 0.1f;
        v[q][j] = vn;
        float xn = fmaf(dt, vn, x_lds[rowv[j] * 512 + colv[q]]);
        x_lds[rowv[j] * 512 + colv[q]] = xn;
        int gi = rg[j] + colv[q];
        pos[gi] = xn;
        vel[gi] = vn;
        if (t == NSTEPS - 1) { out[OFF_XF + gi] = xn; out[OFF_VF + gi] = vn; }
      }
    }
  }

  // ---- converged = ||v_f|| < threshold (gz_p zeroed in last gate phase) ----
#pragma unroll
  for (int j = 0; j < 4; ++j) {
    float s = 0.f;
#pragma unroll
    for (int q = 0; q < 2; ++q) s += v[q][j] * v[q][j];
    s += __shfl_xor(s, 1); s += __shfl_xor(s, 2);
    s += __shfl_xor(s, 4); s += __shfl_xor(s, 8);
    if (li == 0) atomicAdd(&gz_p[rowv[j]], s);
  }
  LGKM0; BAR;
  if (tid < 16) {
    float thr = fabsf(rthr[0]) + 1e-4f;
    out[OFF_CONV + base + tid] = (sqrtf(gz_p[tid]) < thr) ? 1.0f : 0.0f;
  }
}

__global__ void finalize_kernel(const float* __restrict__ gzsum,
                                float* __restrict__ out) {
  int t = threadIdx.x;
  if (t < 17) out[OFF_GZ + t] = gzsum[t] * (1.0f / 4096.0f);
}

extern "C" void kernel_launch(void* const* d_in, const int* in_sizes, int n_in,
                              void* d_out, int out_size, void* d_ws, size_t ws_size,
                              hipStream_t stream) {
  const float* x0     = (const float*)d_in[0];
  const float* noise  = (const float*)d_in[1];
  const float* Wv     = (const float*)d_in[2];
  const float* bv     = (const float*)d_in[3];
  const float* W1     = (const float*)d_in[4];
  const float* b1     = (const float*)d_in[5];
  const float* W2     = (const float*)d_in[6];
  const float* b2     = (const float*)d_in[7];
  const float* Wg1    = (const float*)d_in[8];
  const float* bg1    = (const float*)d_in[9];
  const float* Wg2    = (const float*)d_in[10];
  const float* bg2    = (const float*)d_in[11];
  const float* rdec   = (const float*)d_in[12];
  const float* rdt    = (const float*)d_in[13];
  const float* rspr   = (const float*)d_in[14];
  const float* rthr   = (const float*)d_in[15];
  unsigned short* ws  = (unsigned short*)d_ws;
  float* gz           = (float*)((char*)d_ws + WS_GZ);
  float* out          = (float*)d_out;

  prep_kernel<<<384, 256, 0, stream>>>(Wv, W1, W2, ws);
  main_kernel<<<256, 1024, 0, stream>>>(x0, noise, bv, b1, b2, Wg1, bg1, Wg2, bg2,
                                        rdec, rdt, rspr, rthr, ws, gz, out);
  finalize_kernel<<<1, 32, 0, stream>>>(gz, out);
}